// Round 1
// 136.894 us; speedup vs baseline: 1.0033x; 1.0033x over previous
//
#include <hip/hip_runtime.h>
#include <math.h>

#define NSUB   2048
#define NTRIAL 40
#define NPATH  12341
#define PBLK   1024
#define NFULL  (NPATH / PBLK)          // 12 full iterations (12288 paths)
#define NTAIL  (NPATH - NFULL * PBLK)  // 53 remainder paths

#define LOG2E  1.44269504088896340736f

// ---------------------------------------------------------------------------
// Kernel 1: per-path decode. Monotone path -> packed breakpoints
// (t1,t2,t3) = counts of trials in states <=0, <=1, <=2, and log2 P(path).
// Record: int2 { float log2p (bitcast), int bp }.
// 64-thread blocks so the 12341-thread grid spreads across ~193 CUs.
// ---------------------------------------------------------------------------
__global__ __launch_bounds__(64) void path_kernel(
        const int* __restrict__ paths,
        const float* __restrict__ w_sp,
        const float* __restrict__ w_tr,
        int2* __restrict__ rec) {
    __shared__ float sprior[4];
    __shared__ float str[16];
    const int tid = threadIdx.x;

    if (tid < 4) {
        float m = fmaxf(fmaxf(w_sp[0], w_sp[1]), fmaxf(w_sp[2], w_sp[3]));
        float s = 0.f;
        for (int k = 0; k < 4; k++) s += __expf(w_sp[k] - m);
        sprior[tid] = (w_sp[tid] - (__logf(s) + m)) * LOG2E;
    } else if (tid < 20) {
        int idx = tid - 4, i = idx >> 2, j = idx & 3;
        float m = -1e30f;
        for (int k = i; k < 4; k++) m = fmaxf(m, w_tr[i*4 + k]);
        float s = 0.f;
        for (int k = i; k < 4; k++) s += __expf(w_tr[i*4 + k] - m);
        str[idx] = (j >= i) ? (w_tr[i*4 + j] - (__logf(s) + m)) * LOG2E : 0.f;
    }
    __syncthreads();

    int p = blockIdx.x * 64 + tid;
    if (p >= NPATH) return;

    const int4* pp = (const int4*)(paths + (size_t)p * NTRIAL);
    int st[NTRIAL];
#pragma unroll
    for (int q = 0; q < NTRIAL / 4; q++) {
        int4 v = pp[q];
        st[4*q] = v.x; st[4*q+1] = v.y; st[4*q+2] = v.z; st[4*q+3] = v.w;
    }
    float lp = sprior[st[0]];
    int c0 = (st[0] == 0), c1 = (st[0] <= 1), c2 = (st[0] <= 2);
#pragma unroll
    for (int t = 1; t < NTRIAL; t++) {
        lp += str[st[t-1]*4 + st[t]];
        c0 += (st[t] == 0); c1 += (st[t] <= 1); c2 += (st[t] <= 2);
    }
    rec[p] = make_int2(__float_as_int(lp), c0 | (c1 << 6) | (c2 << 12));
}

// ---------------------------------------------------------------------------
// Kernel 2: one block (1024 thr) per subject.
// log2-numerator(p) = log2p + D1[t1] + D2[t2] + D3[t3]
// where D1[t]=C0[t]-C1[t], D2[t]=C1[t]-C2[t], D3[t]=C2[t]-C3[t]  (the +C3[40]
// constant of the original formulation is uniform across paths and cancels in
// the softmax normalization, so it is dropped entirely).
// D tables computed by wave-parallel shuffle difference-scans (6 steps), not a
// 40-step serial LDS chain. 4 barriers total.
// ---------------------------------------------------------------------------
__global__ __launch_bounds__(1024) void post_kernel(
        const int* __restrict__ resp,
        const float* __restrict__ w_ss,
        const int2* __restrict__ rec,
        float* __restrict__ out) {
    __shared__ float lsr[16];            // log2 p_state_responses
    __shared__ int   rs[NTRIAL];
    __shared__ float D1[NTRIAL + 1], D2[NTRIAL + 1], D3[NTRIAL + 1];
    __shared__ float red[16];
    __shared__ float s_inv;

    const int s = blockIdx.x;
    const int tid = threadIdx.x;
    const int lane = tid & 63, wave = tid >> 6;

    // wave 3 loads responses while wave 0 computes lsr — overlapped
    if (wave == 3 && lane < NTRIAL)
        rs[lane] = resp[(size_t)s * NTRIAL + lane];
    if (tid < 16) {
        const float psr[4][4] = {
            {3.f/9.f, 4.f/9.f, 1.f/9.f, 1.f/9.f},
            {0.f,     4.f/6.f, 1.f/6.f, 1.f/6.f},
            {0.f,     0.f,     0.5f,    0.5f},
            {0.f,     0.f,     0.f,     1.f}};
        int i = tid >> 2, r = tid & 3;
        float m = -1e30f;
        for (int j = 0; j <= i; j++) m = fmaxf(m, w_ss[i*4 + j]);
        float e[4] = {0.f,0.f,0.f,0.f}, ssum = 0.f;
        for (int j = 0; j <= i; j++) { e[j] = __expf(w_ss[i*4 + j] - m); ssum += e[j]; }
        float acc = 0.f;
        for (int j = 0; j <= i; j++) acc += (e[j] / ssum) * psr[j][r];
        lsr[tid] = __builtin_amdgcn_logf(acc);   // log2
    }
    __syncthreads();

    // waves 0..2: D_{w+1}[t] = prefix-scan of (lsr[w][r_t] - lsr[w+1][r_t])
    if (wave < 3) {
        float x = 0.f;
        if (lane < NTRIAL) {
            int rv = rs[lane];
            x = lsr[wave*4 + rv] - lsr[wave*4 + 4 + rv];
        }
#pragma unroll
        for (int off = 1; off < 64; off <<= 1) {
            float y = __shfl_up(x, off, 64);
            if (lane >= off) x += y;
        }
        float* D = (wave == 0) ? D1 : (wave == 1) ? D2 : D3;
        if (lane < NTRIAL) D[lane + 1] = x;
        if (lane == 0)     D[0] = 0.f;
    }
    __syncthreads();

    // ---- load all rec records up front (12 outstanding dwordx2 + tail) ----
    int2 r[NFULL];
#pragma unroll
    for (int i = 0; i < NFULL; i++) r[i] = rec[tid + PBLK * i];
    const bool tail = (tid < NTAIL);
    int2 rt = tail ? rec[NFULL * PBLK + tid] : make_int2(0, 0);

    float nums[NFULL];
    float lsum = 0.f;
#pragma unroll
    for (int i = 0; i < NFULL; i++) {
        int b = r[i].y;
        int t1 = b & 63, t2 = (b >> 6) & 63, t3 = (b >> 12) & 63;
        float v = __builtin_amdgcn_exp2f(
            __int_as_float(r[i].x) + D1[t1] + D2[t2] + D3[t3]);
        nums[i] = v;
        lsum += v;
    }
    float numt = 0.f;
    if (tail) {
        int b = rt.y;
        int t1 = b & 63, t2 = (b >> 6) & 63, t3 = (b >> 12) & 63;
        numt = __builtin_amdgcn_exp2f(
            __int_as_float(rt.x) + D1[t1] + D2[t2] + D3[t3]);
        lsum += numt;
    }

    // wave64 shuffle reduce, then cross-wave (wave-parallel, no serial loop)
#pragma unroll
    for (int off = 32; off > 0; off >>= 1)
        lsum += __shfl_down(lsum, off, 64);
    if (lane == 0) red[wave] = lsum;
    __syncthreads();
    if (tid < 64) {
        float t = (lane < 16) ? red[lane] : 0.f;
#pragma unroll
        for (int off = 8; off > 0; off >>= 1)
            t += __shfl_down(t, off, 64);
        if (lane == 0) s_inv = 1.f / t;
    }
    __syncthreads();
    const float inv = s_inv;

    float* orow = out + (size_t)s * NPATH;
#pragma unroll
    for (int i = 0; i < NFULL; i++)
        __builtin_nontemporal_store(nums[i] * inv, &orow[tid + PBLK * i]);
    if (tail)
        __builtin_nontemporal_store(numt * inv, &orow[NFULL * PBLK + tid]);
}

// ---------------------------------------------------------------------------
extern "C" void kernel_launch(void* const* d_in, const int* in_sizes, int n_in,
                              void* d_out, int out_size, void* d_ws, size_t ws_size,
                              hipStream_t stream) {
    const int*   resp  = (const int*)d_in[0];
    const int*   paths = (const int*)d_in[1];
    const float* w_ss  = (const float*)d_in[2];
    const float* w_sp  = (const float*)d_in[3];
    const float* w_tr  = (const float*)d_in[4];
    float* out = (float*)d_out;

    int2* rec = (int2*)d_ws;   // NPATH records (8 B each)

    path_kernel<<<(NPATH + 63) / 64, 64, 0, stream>>>(paths, w_sp, w_tr, rec);
    post_kernel<<<NSUB, PBLK, 0, stream>>>(resp, w_ss, rec, out);
}